// Round 1
// baseline (226.475 us; speedup 1.0000x reference)
//
#include <hip/hip_runtime.h>
#include <math.h>

#define NJ 24

__global__ __launch_bounds__(256) void fk_kernel(
    const float* __restrict__ theta,        // Bn*NJ*3
    const float* __restrict__ rest_pose,    // NJ*3
    const float* __restrict__ bone_factor,  // NJ-1
    float* __restrict__ kp3d,               // Bn*NJ*3
    float* __restrict__ orient,             // Bn*NJ*9
    float* __restrict__ l2ws,               // Bn*NJ*16
    int Bn)
{
    const int b = blockIdx.x * blockDim.x + threadIdx.x;
    if (b >= Bn) return;

    // Parent of joint j (PARENTS in the reference; compile-time constant).
    constexpr int par[NJ] = {-1,0,0,0,1,2,3,4,5,6,7,8,9,9,9,12,13,14,16,17,18,19,20,21};

    const float* tb = theta + (size_t)b * (NJ * 3);

    // 3x4 affine [R|t] per joint; fully unrolled + constant indices -> registers.
    float L[NJ][12];

    #pragma unroll
    for (int j = 0; j < NJ; ++j) {
        // ---- Rodrigues ----
        const float x = tb[j * 3 + 0];
        const float y = tb[j * 3 + 1];
        const float z = tb[j * 3 + 2];
        const float ang = sqrtf(x * x + y * y + z * z + 1e-12f);
        const float inv = 1.0f / ang;
        const float ux = x * inv, uy = y * inv, uz = z * inv;
        float s, c;
        sincosf(ang, &s, &c);
        const float ic = 1.0f - c;
        const float xx = ic * ux * ux, yy = ic * uy * uy, zz = ic * uz * uz;
        const float xy = ic * ux * uy, xz = ic * ux * uz, yz = ic * uy * uz;
        const float sx = s * ux, sy = s * uy, sz = s * uz;
        const float R00 = c + xx,  R01 = xy - sz, R02 = xz + sy;
        const float R10 = xy + sz, R11 = c + yy,  R12 = yz - sx;
        const float R20 = xz - sy, R21 = yz + sx, R22 = c + zz;

        if (j == 0) {
            L[0][0] = R00; L[0][1] = R01; L[0][2]  = R02; L[0][3]  = rest_pose[0];
            L[0][4] = R10; L[0][5] = R11; L[0][6]  = R12; L[0][7]  = rest_pose[1];
            L[0][8] = R20; L[0][9] = R21; L[0][10] = R22; L[0][11] = rest_pose[2];
        } else {
            const int p = par[j];
            // bone vector scaled by sqrt(bf^2 + 1e-36)
            float bf = bone_factor[j - 1];
            bf = sqrtf(bf * bf + 1e-36f);
            const float bx = (rest_pose[j * 3 + 0] - rest_pose[p * 3 + 0]) * bf;
            const float by = (rest_pose[j * 3 + 1] - rest_pose[p * 3 + 1]) * bf;
            const float bz = (rest_pose[j * 3 + 2] - rest_pose[p * 3 + 2]) * bf;

            const float p0 = L[p][0], p1 = L[p][1], p2  = L[p][2],  p3  = L[p][3];
            const float p4 = L[p][4], p5 = L[p][5], p6  = L[p][6],  p7  = L[p][7];
            const float p8 = L[p][8], p9 = L[p][9], p10 = L[p][10], p11 = L[p][11];

            L[j][0]  = p0 * R00 + p1 * R10 + p2 * R20;
            L[j][1]  = p0 * R01 + p1 * R11 + p2 * R21;
            L[j][2]  = p0 * R02 + p1 * R12 + p2 * R22;
            L[j][3]  = p0 * bx  + p1 * by  + p2 * bz + p3;

            L[j][4]  = p4 * R00 + p5 * R10 + p6 * R20;
            L[j][5]  = p4 * R01 + p5 * R11 + p6 * R21;
            L[j][6]  = p4 * R02 + p5 * R12 + p6 * R22;
            L[j][7]  = p4 * bx  + p5 * by  + p6 * bz + p7;

            L[j][8]  = p8 * R00 + p9 * R10 + p10 * R20;
            L[j][9]  = p8 * R01 + p9 * R11 + p10 * R21;
            L[j][10] = p8 * R02 + p9 * R12 + p10 * R22;
            L[j][11] = p8 * bx  + p9 * by  + p10 * bz + p11;
        }

        // ---- stores ----
        float4* lw = reinterpret_cast<float4*>(l2ws + (size_t)b * (NJ * 16) + j * 16);
        lw[0] = make_float4(L[j][0], L[j][1], L[j][2],  L[j][3]);
        lw[1] = make_float4(L[j][4], L[j][5], L[j][6],  L[j][7]);
        lw[2] = make_float4(L[j][8], L[j][9], L[j][10], L[j][11]);
        lw[3] = make_float4(0.0f, 0.0f, 0.0f, 1.0f);

        float* ob = orient + (size_t)b * (NJ * 9) + j * 9;
        ob[0] = L[j][0]; ob[1] = L[j][1]; ob[2] = L[j][2];
        ob[3] = L[j][4]; ob[4] = L[j][5]; ob[5] = L[j][6];
        ob[6] = L[j][8]; ob[7] = L[j][9]; ob[8] = L[j][10];

        float* kb = kp3d + (size_t)b * (NJ * 3) + j * 3;
        kb[0] = L[j][3]; kb[1] = L[j][7]; kb[2] = L[j][11];
    }
}

extern "C" void kernel_launch(void* const* d_in, const int* in_sizes, int n_in,
                              void* d_out, int out_size, void* d_ws, size_t ws_size,
                              hipStream_t stream) {
    const float* theta       = (const float*)d_in[0];
    const float* rest_pose   = (const float*)d_in[1];
    const float* bone_factor = (const float*)d_in[2];
    // d_in[3] (parents) unused: the topology is a compile-time constant baked
    // into the reference's Python loop as well.

    const int Bn = in_sizes[0] / (NJ * 3);
    const size_t BNJ = (size_t)Bn * NJ;

    float* out    = (float*)d_out;
    float* kp3d   = out;                // BNJ*3
    float* orient = out + BNJ * 3;      // BNJ*9
    float* l2ws   = out + BNJ * 12;     // BNJ*16

    const int block = 256;
    const int grid  = (Bn + block - 1) / block;
    fk_kernel<<<grid, block, 0, stream>>>(theta, rest_pose, bone_factor,
                                          kp3d, orient, l2ws, Bn);
}

// Round 2
// 199.534 us; speedup vs baseline: 1.1350x; 1.1350x over previous
//
#include <hip/hip_runtime.h>
#include <math.h>
#include <stdint.h>

#define NJ 24

__global__ __launch_bounds__(256) void fk_kernel(
    const float* __restrict__ theta,        // Bn*NJ*3
    const float* __restrict__ rest_pose,    // NJ*3
    const float* __restrict__ bone_factor,  // NJ-1
    float* __restrict__ kp3d,               // Bn*NJ*3
    float* __restrict__ orient,             // Bn*NJ*9
    float* __restrict__ l2ws,               // Bn*NJ*16
    int Bn)
{
    const int b = blockIdx.x * blockDim.x + threadIdx.x;
    if (b >= Bn) return;

    constexpr int par[NJ] = {-1,0,0,0,1,2,3,4,5,6,7,8,9,9,9,12,13,14,16,17,18,19,20,21};

    // ---- Prefetch the whole theta item (288 B) into registers: 18 back-to-back
    // float4 loads -> full cache lines consumed immediately, no L1 thrash.
    float t[NJ * 3];
    {
        const float4* tb4 = reinterpret_cast<const float4*>(theta + (size_t)b * (NJ * 3));
        #pragma unroll
        for (int i = 0; i < 18; ++i) {
            const float4 v = tb4[i];
            t[i * 4 + 0] = v.x; t[i * 4 + 1] = v.y;
            t[i * 4 + 2] = v.z; t[i * 4 + 3] = v.w;
        }
    }

    float L[NJ][12];
    float4* lw = reinterpret_cast<float4*>(l2ws + (size_t)b * (NJ * 16));

    #pragma unroll
    for (int j = 0; j < NJ; ++j) {
        // ---- Rodrigues ----
        const float x = t[j * 3 + 0];
        const float y = t[j * 3 + 1];
        const float z = t[j * 3 + 2];
        const float ang = sqrtf(x * x + y * y + z * z + 1e-12f);
        const float inv = 1.0f / ang;
        const float ux = x * inv, uy = y * inv, uz = z * inv;
        float s, c;
        sincosf(ang, &s, &c);
        const float ic = 1.0f - c;
        const float xx = ic * ux * ux, yy = ic * uy * uy, zz = ic * uz * uz;
        const float xy = ic * ux * uy, xz = ic * ux * uz, yz = ic * uy * uz;
        const float sx = s * ux, sy = s * uy, sz = s * uz;
        const float R00 = c + xx,  R01 = xy - sz, R02 = xz + sy;
        const float R10 = xy + sz, R11 = c + yy,  R12 = yz - sx;
        const float R20 = xz - sy, R21 = yz + sx, R22 = c + zz;

        if (j == 0) {
            L[0][0] = R00; L[0][1] = R01; L[0][2]  = R02; L[0][3]  = rest_pose[0];
            L[0][4] = R10; L[0][5] = R11; L[0][6]  = R12; L[0][7]  = rest_pose[1];
            L[0][8] = R20; L[0][9] = R21; L[0][10] = R22; L[0][11] = rest_pose[2];
        } else {
            const int p = par[j];
            float bf = bone_factor[j - 1];
            bf = sqrtf(bf * bf + 1e-36f);
            const float bx = (rest_pose[j * 3 + 0] - rest_pose[p * 3 + 0]) * bf;
            const float by = (rest_pose[j * 3 + 1] - rest_pose[p * 3 + 1]) * bf;
            const float bz = (rest_pose[j * 3 + 2] - rest_pose[p * 3 + 2]) * bf;

            const float p0 = L[p][0], p1 = L[p][1], p2  = L[p][2],  p3  = L[p][3];
            const float p4 = L[p][4], p5 = L[p][5], p6  = L[p][6],  p7  = L[p][7];
            const float p8 = L[p][8], p9 = L[p][9], p10 = L[p][10], p11 = L[p][11];

            L[j][0]  = p0 * R00 + p1 * R10 + p2 * R20;
            L[j][1]  = p0 * R01 + p1 * R11 + p2 * R21;
            L[j][2]  = p0 * R02 + p1 * R12 + p2 * R22;
            L[j][3]  = p0 * bx  + p1 * by  + p2 * bz + p3;

            L[j][4]  = p4 * R00 + p5 * R10 + p6 * R20;
            L[j][5]  = p4 * R01 + p5 * R11 + p6 * R21;
            L[j][6]  = p4 * R02 + p5 * R12 + p6 * R22;
            L[j][7]  = p4 * bx  + p5 * by  + p6 * bz + p7;

            L[j][8]  = p8 * R00 + p9 * R10 + p10 * R20;
            L[j][9]  = p8 * R01 + p9 * R11 + p10 * R21;
            L[j][10] = p8 * R02 + p9 * R12 + p10 * R22;
            L[j][11] = p8 * bx  + p9 * by  + p10 * bz + p11;
        }

        // Only l2ws is written in the main loop: one full 64 B sector per joint,
        // completed by 4 consecutive dwordx4 stores.
        lw[j * 4 + 0] = make_float4(L[j][0], L[j][1], L[j][2],  L[j][3]);
        lw[j * 4 + 1] = make_float4(L[j][4], L[j][5], L[j][6],  L[j][7]);
        lw[j * 4 + 2] = make_float4(L[j][8], L[j][9], L[j][10], L[j][11]);
        lw[j * 4 + 3] = make_float4(0.0f, 0.0f, 0.0f, 1.0f);
    }

    // ---- Epilogue: re-read own l2ws (L2/L3-hot, FETCH counts HBM only) and emit
    // orient + kp3d as dense back-to-back stores so every output line fills
    // within a few instructions (no partial-line evictions).
    // Launder the pointer so LLVM can't store-to-load forward (would blow up
    // register liveness to 288 floats).
    uint64_t lp = (uint64_t)(l2ws + (size_t)b * (NJ * 16));
    asm volatile("" : "+v"(lp));
    const float4* lwr = reinterpret_cast<const float4*>(lp);

    float* ob = orient + (size_t)b * (NJ * 9);
    float* kb = kp3d  + (size_t)b * (NJ * 3);

    #pragma unroll
    for (int j = 0; j < NJ; ++j) {
        const float4 r0 = lwr[j * 4 + 0];
        const float4 r1 = lwr[j * 4 + 1];
        const float4 r2 = lwr[j * 4 + 2];

        ob[j * 9 + 0] = r0.x; ob[j * 9 + 1] = r0.y; ob[j * 9 + 2] = r0.z;
        ob[j * 9 + 3] = r1.x; ob[j * 9 + 4] = r1.y; ob[j * 9 + 5] = r1.z;
        ob[j * 9 + 6] = r2.x; ob[j * 9 + 7] = r2.y; ob[j * 9 + 8] = r2.z;

        kb[j * 3 + 0] = r0.w; kb[j * 3 + 1] = r1.w; kb[j * 3 + 2] = r2.w;
    }
}

extern "C" void kernel_launch(void* const* d_in, const int* in_sizes, int n_in,
                              void* d_out, int out_size, void* d_ws, size_t ws_size,
                              hipStream_t stream) {
    const float* theta       = (const float*)d_in[0];
    const float* rest_pose   = (const float*)d_in[1];
    const float* bone_factor = (const float*)d_in[2];

    const int Bn = in_sizes[0] / (NJ * 3);
    const size_t BNJ = (size_t)Bn * NJ;

    float* out    = (float*)d_out;
    float* kp3d   = out;                // BNJ*3
    float* orient = out + BNJ * 3;      // BNJ*9
    float* l2ws   = out + BNJ * 12;     // BNJ*16

    const int block = 256;
    const int grid  = (Bn + block - 1) / block;
    fk_kernel<<<grid, block, 0, stream>>>(theta, rest_pose, bone_factor,
                                          kp3d, orient, l2ws, Bn);
}

// Round 3
// 112.057 us; speedup vs baseline: 2.0211x; 1.7806x over previous
//
#include <hip/hip_runtime.h>
#include <math.h>

#define NJ  24
#define IPB 64      // items (batch elements) per block
#define TPB 256
#define CJ  8       // joints per chunk
#define NCH 3       // chunks

__global__ __launch_bounds__(TPB) void fk_kernel(
    const float* __restrict__ theta,        // Bn*NJ*3
    const float* __restrict__ rest_pose,    // NJ*3
    const float* __restrict__ bone_factor,  // NJ-1
    float* __restrict__ kp3d,               // Bn*NJ*3
    float* __restrict__ orient,             // Bn*NJ*9
    float* __restrict__ l2ws,               // Bn*NJ*16
    int Bn)
{
    constexpr int par[NJ] = {-1,0,0,0,1,2,3,4,5,6,7,8,9,9,9,12,13,14,16,17,18,19,20,21};

    // One LDS tile: per item-chunk 8 joints x 4 rows (float4) = 32 f4, +1 pad.
    __shared__ float4 ls[IPB * 33];

    const int tid   = threadIdx.x;
    const int item0 = blockIdx.x * IPB;
    if (item0 >= Bn) return;

    float L[NJ][12];   // per-lane chain state; constant-indexed -> registers

    #pragma unroll
    for (int c = 0; c < NCH; ++c) {
        // ---------- compute: wave 0, one item per lane ----------
        if (tid < IPB) {
            const int b = item0 + tid;
            // per-chunk theta: 24 floats = 6 float4, coalesced across lanes
            float t[CJ * 3];
            {
                const float4* tb4 = reinterpret_cast<const float4*>(
                    theta + (size_t)b * (NJ * 3) + c * (CJ * 3));
                #pragma unroll
                for (int i = 0; i < (CJ * 3) / 4; ++i) {
                    const float4 v = tb4[i];
                    t[i*4+0] = v.x; t[i*4+1] = v.y; t[i*4+2] = v.z; t[i*4+3] = v.w;
                }
            }

            #pragma unroll
            for (int jj = 0; jj < CJ; ++jj) {
                const int j = c * CJ + jj;
                const float x = t[jj*3+0], y = t[jj*3+1], z = t[jj*3+2];
                const float ang = sqrtf(x*x + y*y + z*z + 1e-12f);
                const float inv = 1.0f / ang;
                const float ux = x*inv, uy = y*inv, uz = z*inv;
                float s, cs;
                sincosf(ang, &s, &cs);
                const float ic = 1.0f - cs;
                const float xx = ic*ux*ux, yy = ic*uy*uy, zz = ic*uz*uz;
                const float xy = ic*ux*uy, xz = ic*ux*uz, yz = ic*uy*uz;
                const float sx = s*ux, sy = s*uy, sz = s*uz;
                const float R00 = cs+xx,  R01 = xy-sz, R02 = xz+sy;
                const float R10 = xy+sz,  R11 = cs+yy, R12 = yz-sx;
                const float R20 = xz-sy,  R21 = yz+sx, R22 = cs+zz;

                if (j == 0) {
                    L[0][0]=R00; L[0][1]=R01; L[0][2] =R02; L[0][3] =rest_pose[0];
                    L[0][4]=R10; L[0][5]=R11; L[0][6] =R12; L[0][7] =rest_pose[1];
                    L[0][8]=R20; L[0][9]=R21; L[0][10]=R22; L[0][11]=rest_pose[2];
                } else {
                    const int p = par[j];
                    float bf = bone_factor[j - 1];
                    bf = sqrtf(bf*bf + 1e-36f);
                    const float bx = (rest_pose[j*3+0] - rest_pose[p*3+0]) * bf;
                    const float by = (rest_pose[j*3+1] - rest_pose[p*3+1]) * bf;
                    const float bz = (rest_pose[j*3+2] - rest_pose[p*3+2]) * bf;

                    const float p0=L[p][0], p1=L[p][1], p2 =L[p][2],  p3 =L[p][3];
                    const float p4=L[p][4], p5=L[p][5], p6 =L[p][6],  p7 =L[p][7];
                    const float p8=L[p][8], p9=L[p][9], p10=L[p][10], p11=L[p][11];

                    L[j][0]  = p0*R00 + p1*R10 + p2*R20;
                    L[j][1]  = p0*R01 + p1*R11 + p2*R21;
                    L[j][2]  = p0*R02 + p1*R12 + p2*R22;
                    L[j][3]  = p0*bx  + p1*by  + p2*bz + p3;
                    L[j][4]  = p4*R00 + p5*R10 + p6*R20;
                    L[j][5]  = p4*R01 + p5*R11 + p6*R21;
                    L[j][6]  = p4*R02 + p5*R12 + p6*R22;
                    L[j][7]  = p4*bx  + p5*by  + p6*bz + p7;
                    L[j][8]  = p8*R00 + p9*R10 + p10*R20;
                    L[j][9]  = p8*R01 + p9*R11 + p10*R21;
                    L[j][10] = p8*R02 + p9*R12 + p10*R22;
                    L[j][11] = p8*bx  + p9*by  + p10*bz + p11;
                }

                // stage 4x4 row-major into LDS
                ls[tid*33 + jj*4 + 0] = make_float4(L[j][0], L[j][1], L[j][2],  L[j][3]);
                ls[tid*33 + jj*4 + 1] = make_float4(L[j][4], L[j][5], L[j][6],  L[j][7]);
                ls[tid*33 + jj*4 + 2] = make_float4(L[j][8], L[j][9], L[j][10], L[j][11]);
                ls[tid*33 + jj*4 + 3] = make_float4(0.0f, 0.0f, 0.0f, 1.0f);
            }
        }
        __syncthreads();

        // ---------- flush l2ws: 2048 f4, lane-contiguous ----------
        {
            float4* g4 = reinterpret_cast<float4*>(l2ws);
            #pragma unroll
            for (int k = 0; k < 8; ++k) {
                const int g   = k * TPB + tid;
                const int i   = g >> 5;        // item within block
                const int off = g & 31;        // f4 within item-chunk
                g4[(size_t)(item0 + i) * 96 + c * 32 + off] = ls[i * 33 + off];
            }
        }

        // ---------- flush orient: 1152 f4 (72 floats/item-chunk) ----------
        {
            const float* lf = reinterpret_cast<const float*>(ls);
            float4* g4 = reinterpret_cast<float4*>(orient);
            #pragma unroll
            for (int k = 0; k < 5; ++k) {
                const int g = k * TPB + tid;
                if (k < 4 || g < IPB * 18) {
                    const int i  = g / 18;
                    const int o4 = g % 18;
                    float v[4];
                    #pragma unroll
                    for (int m = 0; m < 4; ++m) {
                        const int f  = o4 * 4 + m;     // [0,72)
                        const int jj = f / 9;
                        const int mm = f % 9;
                        const int r  = mm / 3, col = mm % 3;
                        v[m] = lf[(i * 33 + jj * 4 + r) * 4 + col];
                    }
                    g4[(size_t)(item0 + i) * 54 + c * 18 + o4] =
                        make_float4(v[0], v[1], v[2], v[3]);
                }
            }
        }

        // ---------- flush kp3d: 384 f4 (24 floats/item-chunk) ----------
        {
            const float* lf = reinterpret_cast<const float*>(ls);
            float4* g4 = reinterpret_cast<float4*>(kp3d);
            #pragma unroll
            for (int k = 0; k < 2; ++k) {
                const int g = k * TPB + tid;
                if (k < 1 || g < IPB * 6) {
                    const int i  = g / 6;
                    const int o4 = g % 6;
                    float v[4];
                    #pragma unroll
                    for (int m = 0; m < 4; ++m) {
                        const int f  = o4 * 4 + m;     // [0,24)
                        const int jj = f / 3;
                        const int r  = f % 3;
                        v[m] = lf[(i * 33 + jj * 4 + r) * 4 + 3];
                    }
                    g4[(size_t)(item0 + i) * 18 + c * 6 + o4] =
                        make_float4(v[0], v[1], v[2], v[3]);
                }
            }
        }

        if (c < NCH - 1) __syncthreads();
    }
}

extern "C" void kernel_launch(void* const* d_in, const int* in_sizes, int n_in,
                              void* d_out, int out_size, void* d_ws, size_t ws_size,
                              hipStream_t stream) {
    const float* theta       = (const float*)d_in[0];
    const float* rest_pose   = (const float*)d_in[1];
    const float* bone_factor = (const float*)d_in[2];

    const int Bn = in_sizes[0] / (NJ * 3);
    const size_t BNJ = (size_t)Bn * NJ;

    float* out    = (float*)d_out;
    float* kp3d   = out;                // BNJ*3
    float* orient = out + BNJ * 3;      // BNJ*9
    float* l2ws   = out + BNJ * 12;     // BNJ*16

    const int grid = (Bn + IPB - 1) / IPB;
    fk_kernel<<<grid, TPB, 0, stream>>>(theta, rest_pose, bone_factor,
                                        kp3d, orient, l2ws, Bn);
}